// Round 1
// baseline (331.967 us; speedup 1.0000x reference)
//
#include <hip/hip_runtime.h>
#include <math.h>

#define N_PTS 8192
#define TPB 256
#define RPB 4   // rows per block: amortizes j-stream loads 4x

__device__ inline float wave_reduce_sum(float v) {
    #pragma unroll
    for (int off = 32; off > 0; off >>= 1)
        v += __shfl_down(v, off, 64);
    return v;
}

__global__ void precompute_cs(const float* __restrict__ theta,
                              float* __restrict__ cs,
                              float* __restrict__ sn) {
    int i = blockIdx.x * blockDim.x + threadIdx.x;
    if (i < N_PTS) {
        float t = theta[i];
        cs[i] = cosf(t);
        sn[i] = sinf(t);
    }
}

__global__ __launch_bounds__(TPB) void geo_kernel(
    const float* __restrict__ theta,
    const float* __restrict__ tau,
    const float* __restrict__ cs,
    const float* __restrict__ sn,
    float* __restrict__ out)   // [theta_out(N) | tau_out(N) | attn(N*N)]
{
    constexpr float LAMBDA   = 2.5f;
    constexpr float REPEL    = 0.15f;
    constexpr float EPS      = 0.1f;
    constexpr float NORM_EPS = 1e-8f;
    constexpr float TAUW     = 0.3f;
    constexpr float TWO_PI   = 6.28318530717958647692f;

    const int tid  = threadIdx.x;
    const int row0 = blockIdx.x * RPB;

    float* theta_out = out;
    float* tau_out   = out + N_PTS;
    float* attn      = out + 2 * N_PTS;

    float th_i[RPB], ta_i[RPB], c_i[RPB], s_i[RPB];
    #pragma unroll
    for (int r = 0; r < RPB; ++r) {
        th_i[r] = theta[row0 + r];
        ta_i[r] = tau[row0 + r];
        c_i[r]  = cs[row0 + r];
        s_i[r]  = sn[row0 + r];
    }

    float a_sum[RPB], a_x[RPB], a_y[RPB], a_t[RPB], rp_x[RPB], rp_y[RPB];
    #pragma unroll
    for (int r = 0; r < RPB; ++r) {
        a_sum[r] = 0.f; a_x[r] = 0.f; a_y[r] = 0.f;
        a_t[r]  = 0.f; rp_x[r] = 0.f; rp_y[r] = 0.f;
    }

    // ---- Phase 1: accumulate rowsum, attn-weighted sums, repulsion sums ----
    for (int j = tid; j < N_PTS; j += TPB) {
        float th_j = theta[j];
        float ta_j = tau[j];
        float c_j  = cs[j];
        float s_j  = sn[j];
        #pragma unroll
        for (int r = 0; r < RPB; ++r) {
            const int i = row0 + r;
            float diff = fabsf(th_i[r] - th_j);
            float dth  = fminf(diff, TWO_PI - diff);
            float dta  = fabsf(ta_i[r] - ta_j);
            float score = (j == i) ? 0.f : __expf(-LAMBDA * (dth + TAUW * dta));
            a_sum[r] += score;
            a_x[r]   += score * c_j;
            a_y[r]   += score * s_j;
            a_t[r]   += score * ta_j;
            // repulsion (independent of rowsum normalization)
            float d   = dth + EPS;
            float dx  = c_i[r] - c_j;
            float dy  = s_i[r] - s_j;
            float nrm = sqrtf(dx * dx + dy * dy) + NORM_EPS;
            float inv = (j == i) ? 0.f : __fdividef(REPEL, d * d * nrm);
            rp_x[r] += inv * dx;
            rp_y[r] += inv * dy;
        }
    }

    // ---- Block reduction: 6 scalars per row ----
    __shared__ float red[RPB][6][TPB / 64];
    __shared__ float inv_s[RPB];
    const int wave = tid >> 6;
    const int lane = tid & 63;
    #pragma unroll
    for (int r = 0; r < RPB; ++r) {
        float v0 = wave_reduce_sum(a_sum[r]);
        float v1 = wave_reduce_sum(a_x[r]);
        float v2 = wave_reduce_sum(a_y[r]);
        float v3 = wave_reduce_sum(a_t[r]);
        float v4 = wave_reduce_sum(rp_x[r]);
        float v5 = wave_reduce_sum(rp_y[r]);
        if (lane == 0) {
            red[r][0][wave] = v0;
            red[r][1][wave] = v1;
            red[r][2][wave] = v2;
            red[r][3][wave] = v3;
            red[r][4][wave] = v4;
            red[r][5][wave] = v5;
        }
    }
    __syncthreads();

    if (tid < RPB) {
        const int r = tid;
        float s = 0.f, x = 0.f, y = 0.f, t = 0.f, rx = 0.f, ry = 0.f;
        #pragma unroll
        for (int w = 0; w < TPB / 64; ++w) {
            s  += red[r][0][w];
            x  += red[r][1][w];
            y  += red[r][2][w];
            t  += red[r][3][w];
            rx += red[r][4][w];
            ry += red[r][5][w];
        }
        float invsum = 1.0f / s;
        float fx = x * invsum + rx;
        float fy = y * invsum + ry;
        theta_out[row0 + r] = atan2f(fy, fx);
        tau_out[row0 + r]   = t * invsum;
        inv_s[r] = invsum;
    }
    __syncthreads();

    float invs[RPB];
    #pragma unroll
    for (int r = 0; r < RPB; ++r) invs[r] = inv_s[r];

    // ---- Phase 2: recompute scores, write normalized attn (268 MB) ----
    for (int j = tid; j < N_PTS; j += TPB) {
        float th_j = theta[j];
        float ta_j = tau[j];
        #pragma unroll
        for (int r = 0; r < RPB; ++r) {
            const int i = row0 + r;
            float diff = fabsf(th_i[r] - th_j);
            float dth  = fminf(diff, TWO_PI - diff);
            float dta  = fabsf(ta_i[r] - ta_j);
            float score = (j == i) ? 0.f : __expf(-LAMBDA * (dth + TAUW * dta));
            attn[(size_t)i * N_PTS + j] = score * invs[r];
        }
    }
}

extern "C" void kernel_launch(void* const* d_in, const int* in_sizes, int n_in,
                              void* d_out, int out_size, void* d_ws, size_t ws_size,
                              hipStream_t stream) {
    const float* theta = (const float*)d_in[0];
    const float* tau   = (const float*)d_in[1];
    float* cs  = (float*)d_ws;          // 8192 floats
    float* sn  = cs + N_PTS;            // 8192 floats
    float* out = (float*)d_out;

    precompute_cs<<<N_PTS / 256, 256, 0, stream>>>(theta, cs, sn);
    geo_kernel<<<N_PTS / RPB, TPB, 0, stream>>>(theta, tau, cs, sn, out);
}

// Round 2
// 299.866 us; speedup vs baseline: 1.1070x; 1.1070x over previous
//
#include <hip/hip_runtime.h>
#include <math.h>

#define N_PTS 8192
#define TPB 256
#define RPB 4   // rows per block in phase 1

// constants
#define C_LAMBDA   2.5f
#define C_REPEL    0.15f
#define C_EPS      0.1f
#define C_NORM_EPS 1e-8f
#define C_TAUW     0.3f
#define C_TWO_PI   6.28318530717958647692f
#define C_NEG_L_LOG2E (-3.60673760222240625f)   // -2.5 * log2(e)

__device__ __forceinline__ float fast_exp2(float x) {
#if __has_builtin(__builtin_amdgcn_exp2f)
    return __builtin_amdgcn_exp2f(x);
#else
    return exp2f(x);
#endif
}
__device__ __forceinline__ float fast_sqrt(float x) {
#if __has_builtin(__builtin_amdgcn_sqrtf)
    return __builtin_amdgcn_sqrtf(x);
#else
    return sqrtf(x);
#endif
}
__device__ __forceinline__ float fast_rcp(float x) {
#if __has_builtin(__builtin_amdgcn_rcpf)
    return __builtin_amdgcn_rcpf(x);
#else
    return __fdividef(1.0f, x);
#endif
}
__device__ __forceinline__ float fast_log2(float x) {
#if __has_builtin(__builtin_amdgcn_logf)
    return __builtin_amdgcn_logf(x);   // v_log_f32 = log2
#else
    return log2f(x);
#endif
}

__device__ __forceinline__ float wave_reduce_sum(float v) {
    #pragma unroll
    for (int off = 32; off > 0; off >>= 1)
        v += __shfl_down(v, off, 64);
    return v;
}

// Pack j-stream: pk[j] = {theta, tau, cos, sin}; pk2[j] = {theta, tau}
__global__ void pack_kernel(const float* __restrict__ theta,
                            const float* __restrict__ tau,
                            float4* __restrict__ pk,
                            float2* __restrict__ pk2) {
    int i = blockIdx.x * blockDim.x + threadIdx.x;
    float t = theta[i];
    float u = tau[i];
    pk[i]  = make_float4(t, u, cosf(t), sinf(t));
    pk2[i] = make_float2(t, u);
}

// Phase 1: per-row reductions -> theta_out, tau_out, invsum
__global__ __launch_bounds__(TPB) void phase1_kernel(
    const float4* __restrict__ pk,
    float* __restrict__ out,        // [theta_out(N) | tau_out(N) | ...]
    float* __restrict__ invsum)
{
    const int tid  = threadIdx.x;
    const int row0 = blockIdx.x * RPB;

    float th_i[RPB], ta_i[RPB], c_i[RPB], s_i[RPB];
    #pragma unroll
    for (int r = 0; r < RPB; ++r) {
        float4 p = pk[row0 + r];
        th_i[r] = p.x; ta_i[r] = p.y; c_i[r] = p.z; s_i[r] = p.w;
    }

    float a_sum[RPB], a_x[RPB], a_y[RPB], a_t[RPB], rp_x[RPB], rp_y[RPB];
    #pragma unroll
    for (int r = 0; r < RPB; ++r) {
        a_sum[r] = 0.f; a_x[r] = 0.f; a_y[r] = 0.f;
        a_t[r] = 0.f; rp_x[r] = 0.f; rp_y[r] = 0.f;
    }

    // j-sweep with one-iteration register prefetch; diagonal flows through
    // (score=1 at j==i, repulsion self-term contributes exactly 0) and the
    // attention self-contribution is subtracted in the finalize step.
    float4 cur = pk[tid];
    #pragma unroll 2
    for (int k = 0; k < N_PTS / TPB; ++k) {
        float4 nxt = pk[(tid + (k + 1) * TPB) & (N_PTS - 1)];
        #pragma unroll
        for (int r = 0; r < RPB; ++r) {
            float ad    = fabsf(th_i[r] - cur.x);
            float dth   = fminf(ad, C_TWO_PI - ad);
            float t     = fmaf(fabsf(ta_i[r] - cur.y), C_TAUW, dth);
            float score = fast_exp2(t * C_NEG_L_LOG2E);
            a_sum[r] += score;
            a_x[r]   = fmaf(score, cur.z, a_x[r]);
            a_y[r]   = fmaf(score, cur.w, a_y[r]);
            a_t[r]   = fmaf(score, cur.y, a_t[r]);

            float d   = dth + C_EPS;
            float dx  = c_i[r] - cur.z;
            float dy  = s_i[r] - cur.w;
            float q   = fmaf(dx, dx, dy * dy);
            float nrm = fast_sqrt(q) + C_NORM_EPS;
            float inv = fast_rcp(d * d * nrm);   // REPEL folded in at finalize
            rp_x[r] = fmaf(inv, dx, rp_x[r]);
            rp_y[r] = fmaf(inv, dy, rp_y[r]);
        }
        cur = nxt;
    }

    __shared__ float red[RPB][6][TPB / 64];
    const int wave = tid >> 6;
    const int lane = tid & 63;
    #pragma unroll
    for (int r = 0; r < RPB; ++r) {
        float v0 = wave_reduce_sum(a_sum[r]);
        float v1 = wave_reduce_sum(a_x[r]);
        float v2 = wave_reduce_sum(a_y[r]);
        float v3 = wave_reduce_sum(a_t[r]);
        float v4 = wave_reduce_sum(rp_x[r]);
        float v5 = wave_reduce_sum(rp_y[r]);
        if (lane == 0) {
            red[r][0][wave] = v0; red[r][1][wave] = v1; red[r][2][wave] = v2;
            red[r][3][wave] = v3; red[r][4][wave] = v4; red[r][5][wave] = v5;
        }
    }
    __syncthreads();

    if (tid < RPB) {
        const int r = tid;
        float s = 0.f, x = 0.f, y = 0.f, t = 0.f, rx = 0.f, ry = 0.f;
        #pragma unroll
        for (int w = 0; w < TPB / 64; ++w) {
            s  += red[r][0][w]; x  += red[r][1][w]; y  += red[r][2][w];
            t  += red[r][3][w]; rx += red[r][4][w]; ry += red[r][5][w];
        }
        // subtract the j==i attention self-contribution (score == 1)
        float4 p = pk[row0 + r];
        s -= 1.0f;
        x -= p.z;
        y -= p.w;
        t -= p.y;
        float invr = 1.0f / s;
        float fx = fmaf(x, invr, C_REPEL * rx);
        float fy = fmaf(y, invr, C_REPEL * ry);
        out[row0 + r]         = atan2f(fy, fx);   // theta_out
        out[N_PTS + row0 + r] = t * invr;         // tau_out
        invsum[row0 + r]      = invr;
    }
}

// Phase 2: one block per row, streaming write of normalized attn
__global__ __launch_bounds__(TPB) void phase2_kernel(
    const float2* __restrict__ pk2,
    const float* __restrict__ invsum,
    float* __restrict__ attn)
{
    const int i   = blockIdx.x;
    const int tid = threadIdx.x;
    float2 pi   = pk2[i];            // wave-uniform
    float th_i  = pi.x;
    float ta_i  = pi.y;
    float l2inv = fast_log2(invsum[i]);   // fold normalization into exp2
    float* __restrict__ row = attn + (size_t)i * N_PTS;

    float2 cur = pk2[tid];
    #pragma unroll 4
    for (int k = 0; k < N_PTS / TPB; ++k) {
        const int j = tid + k * TPB;
        float2 nxt = pk2[(j + TPB) & (N_PTS - 1)];
        float ad  = fabsf(th_i - cur.x);
        float dth = fminf(ad, C_TWO_PI - ad);
        float t   = fmaf(fabsf(ta_i - cur.y), C_TAUW, dth);
        float v   = fast_exp2(fmaf(t, C_NEG_L_LOG2E, l2inv));
        row[j] = (j == i) ? 0.0f : v;
        cur = nxt;
    }
}

extern "C" void kernel_launch(void* const* d_in, const int* in_sizes, int n_in,
                              void* d_out, int out_size, void* d_ws, size_t ws_size,
                              hipStream_t stream) {
    const float* theta = (const float*)d_in[0];
    const float* tau   = (const float*)d_in[1];

    float4* pk     = (float4*)d_ws;                          // 128 KB
    float2* pk2    = (float2*)((char*)d_ws + 128 * 1024);    //  64 KB
    float*  invsum = (float*)((char*)d_ws + 192 * 1024);     //  32 KB
    float*  out    = (float*)d_out;
    float*  attn   = out + 2 * N_PTS;

    pack_kernel<<<N_PTS / 256, 256, 0, stream>>>(theta, tau, pk, pk2);
    phase1_kernel<<<N_PTS / RPB, TPB, 0, stream>>>(pk, out, invsum);
    phase2_kernel<<<N_PTS, TPB, 0, stream>>>(pk2, invsum, attn);
}